// Round 1
// baseline (258.384 us; speedup 1.0000x reference)
//
#include <hip/hip_runtime.h>

typedef __bf16 bf16x8 __attribute__((ext_vector_type(8)));
typedef float f32x4 __attribute__((ext_vector_type(4)));
typedef unsigned short u16x8 __attribute__((ext_vector_type(8)));
typedef unsigned short u16x4 __attribute__((ext_vector_type(4)));
typedef unsigned short u16;
typedef unsigned int u32;

// S=2048, B=2, H=1024, NH=16, HD=64, SCALE=32 (exact)
// Inputs fp32, output fp32. Internal: bf16 MFMA, fp32 accum.
// Softmax is max-free (scores tightly bounded); log2(e) folded into q gate -> exp2 direct.

#define LOG2E 1.4426950408889634f

__device__ __forceinline__ float b2f(u16 u) {
  union { unsigned int i; float f; } x; x.i = ((unsigned int)u) << 16; return x.f;
}
__device__ __forceinline__ u16 f2b(float f) {
  union { float f; unsigned int i; } x; x.f = f;
  unsigned int r = (x.i + 0x7fffu + ((x.i >> 16) & 1u)) >> 16;
  return (u16)r;
}
__device__ __forceinline__ float sigm(float x) { return 1.0f / (1.0f + __expf(-x)); }
__device__ __forceinline__ u32 cvtpk(float lo, float hi) {
  u32 r; asm("v_cvt_pk_bf16_f32 %0, %1, %2" : "=v"(r) : "v"(lo), "v"(hi)); return r;
}

__device__ __forceinline__ void async16(u16* lds, const u16* g) {
  __builtin_amdgcn_global_load_lds((const __attribute__((address_space(1))) void*)g,
                                   (__attribute__((address_space(3))) void*)lds, 16, 0, 0);
}

// ---- kernel 0: all fp32->bf16 conversions in one launch (grid 18432)
__global__ __launch_bounds__(256) void k_cvt_all(const float4* __restrict__ q, u16x4* __restrict__ qd,
                                                 const float4* __restrict__ w, u16x4* __restrict__ wd,
                                                 const float4* __restrict__ k, u16x4* __restrict__ kd,
                                                 const float4* __restrict__ v, u16x4* __restrict__ vd) {
  int b = blockIdx.x;
  const float4* s; u16x4* d; int i;
  if (b < 8192)       { s = q; d = qd; i = b * 256 + threadIdx.x; }
  else if (b < 10240) { s = w; d = wd; i = (b - 8192) * 256 + threadIdx.x; }
  else if (b < 14336) { s = k; d = kd; i = (b - 10240) * 256 + threadIdx.x; }
  else                { s = v; d = vd; i = (b - 14336) * 256 + threadIdx.x; }
  float4 x = s[i];
  u16x4 o; o[0] = f2b(x.x); o[1] = f2b(x.y); o[2] = f2b(x.z); o[3] = f2b(x.w);
  d[i] = o;
}

// ---- kernel 1: h = sigmoid(vs) @ vq_w.T + vq_b   (wave per row, 512 blocks)
__global__ __launch_bounds__(256) void k_h(const float* __restrict__ vs,
                                           const float* __restrict__ vq_w,
                                           const float* __restrict__ vq_b,
                                           float* __restrict__ h) {
  __shared__ float svs[1024];
  int t = threadIdx.x;
  for (int i = t; i < 1024; i += 256) svs[i] = sigm(vs[i]);
  __syncthreads();
  int wave = t >> 6, lane = t & 63;
  int row = blockIdx.x * 4 + wave;
  const float4* w4 = (const float4*)(vq_w + (size_t)row * 1024);
  const float4* s4 = (const float4*)svs;
  float acc = 0.f;
#pragma unroll
  for (int k = 0; k < 4; ++k) {
    float4 w = w4[k * 64 + lane];
    float4 s = s4[k * 64 + lane];
    acc += w.x * s.x + w.y * s.y + w.z * s.z + w.w * s.w;
  }
#pragma unroll
  for (int off = 1; off < 64; off <<= 1) acc += __shfl_xor(acc, off);
  if (lane == 0) h[row] = acc + vq_b[row];
}

// ---- kernel 3: qpre = query @ ql_w^T, split-K=2 (grid 512: kh = bx>>8)
__global__ __launch_bounds__(256) void k_gemm(const u16* __restrict__ A,    // 4096 x 2048 bf16
                                              const u16* __restrict__ Bt,   // 1024 x 2048 bf16
                                              u16* __restrict__ C) {        // 2 x (4096 x 1024)
  __shared__ __align__(16) u16 As[128 * 32];
  __shared__ __align__(16) u16 Bs[128 * 32];
  int tid = threadIdx.x;
  int wave = tid >> 6, lane = tid & 63;
  int l15 = lane & 15, quad = lane >> 4;
  int bx = blockIdx.x & 255;
  int kh = blockIdx.x >> 8;
  int kofs = kh << 10;
  int m0 = (bx >> 3) * 128;
  int n0 = (bx & 7) * 128;
  int wm = (wave >> 1) * 64, wn = (wave & 1) * 64;
  f32x4 acc[4][4] = {};
  int c1 = tid, c2 = tid + 256;
  const u16* ga1 = A + (size_t)(m0 + (c1 >> 2)) * 2048 + kofs + (c1 & 3) * 8;
  const u16* ga2 = A + (size_t)(m0 + (c2 >> 2)) * 2048 + kofs + (c2 & 3) * 8;
  const u16* gb1 = Bt + (size_t)(n0 + (c1 >> 2)) * 2048 + kofs + (c1 & 3) * 8;
  const u16* gb2 = Bt + (size_t)(n0 + (c2 >> 2)) * 2048 + kofs + (c2 & 3) * 8;
  u16* lA1 = As + wave * 512;
  u16* lA2 = As + 2048 + wave * 512;
  u16* lB1 = Bs + wave * 512;
  u16* lB2 = Bs + 2048 + wave * 512;
  for (int kt = 0; kt < 32; ++kt) {
    async16(lA1, ga1); async16(lA2, ga2);
    async16(lB1, gb1); async16(lB2, gb2);
    ga1 += 32; ga2 += 32; gb1 += 32; gb2 += 32;
    __syncthreads();
    bf16x8 af[4], bfr[4];
#pragma unroll
    for (int mt = 0; mt < 4; ++mt)
      af[mt] = *(const bf16x8*)(As + (wm + mt * 16 + l15) * 32 + quad * 8);
#pragma unroll
    for (int nt = 0; nt < 4; ++nt)
      bfr[nt] = *(const bf16x8*)(Bs + (wn + nt * 16 + l15) * 32 + quad * 8);
#pragma unroll
    for (int mt = 0; mt < 4; ++mt)
#pragma unroll
      for (int nt = 0; nt < 4; ++nt)
        acc[mt][nt] = __builtin_amdgcn_mfma_f32_16x16x32_bf16(af[mt], bfr[nt], acc[mt][nt], 0, 0, 0);
    __syncthreads();
  }
  u16* Cp = C + (size_t)kh * 4096 * 1024;
#pragma unroll
  for (int mt = 0; mt < 4; ++mt) {
#pragma unroll
    for (int r = 0; r < 4; ++r) {
      int m = m0 + wm + mt * 16 + quad * 4 + r;
      u16* crow = Cp + (size_t)m * 1024 + n0 + wn + l15;
#pragma unroll
      for (int nt = 0; nt < 4; ++nt) crow[nt * 16] = f2b(acc[mt][nt][r]);
    }
  }
}

// ---- kernel 4: LN((qpre0+qpre1)+ql_b)*ln_g+ln_b, * sigm(qs)*sigm(ks)*log2e/32 -> qatt (b,h,s,hd)
__global__ __launch_bounds__(256) void k_ln(const u16* __restrict__ qpre0,
                                            const u16* __restrict__ qpre1,
                                            const float* __restrict__ ql_b,
                                            const float* __restrict__ ln_g,
                                            const float* __restrict__ ln_b,
                                            const float* __restrict__ qs,
                                            const float* __restrict__ ks,
                                            u16* __restrict__ qatt) {
  int row = blockIdx.x;   // row = s*2 + b
  int t = threadIdx.x;
  u16x4 a4 = *(const u16x4*)(qpre0 + (size_t)row * 1024 + t * 4);
  u16x4 b4 = *(const u16x4*)(qpre1 + (size_t)row * 1024 + t * 4);
  float v[4];
  float s = 0.f, ss = 0.f;
#pragma unroll
  for (int j = 0; j < 4; ++j) {
    v[j] = b2f(a4[j]) + b2f(b4[j]) + ql_b[t * 4 + j];
    s += v[j]; ss += v[j] * v[j];
  }
#pragma unroll
  for (int off = 1; off < 64; off <<= 1) { s += __shfl_xor(s, off); ss += __shfl_xor(ss, off); }
  __shared__ float red[8];
  int wv = t >> 6, ln = t & 63;
  if (ln == 0) { red[wv] = s; red[4 + wv] = ss; }
  __syncthreads();
  s = red[0] + red[1] + red[2] + red[3];
  ss = red[4] + red[5] + red[6] + red[7];
  float mu = s * (1.f / 1024.f);
  float rstd = rsqrtf(ss * (1.f / 1024.f) - mu * mu + 1e-12f);
  int sidx = row >> 1, b = row & 1;
  int ch0 = t * 4;
  int hh = ch0 >> 6, hd0 = ch0 & 63;
  u16* dst = qatt + ((size_t)(b * 16 + hh) * 2048 + sidx) * 64 + hd0;
#pragma unroll
  for (int j = 0; j < 4; ++j) {
    int ch = ch0 + j;
    float gate = sigm(qs[ch]) * sigm(ks[ch]) * (LOG2E / 32.0f);
    float y = (v[j] - mu) * rstd * ln_g[ch] + ln_b[ch];
    dst[j] = f2b(y * gate);
  }
}

// ---- kernel 5: flash attention, swapped-QK in-register softmax.
// mfma(K,Q) puts P[qrow=l15][16 keys] per lane == PV A-operand layout -> no P LDS round-trip.
// K consumed directly from global as A-fragments (16B contiguous, L2-resident), reg double-buffered.
// Only V staged in LDS (transpose needed), pi-permuted cols to match P's key order, XOR-swizzled rows.
// grid 512: bh = bx & 31 (XCD L2 locality), qt = bx>>5. One barrier/iter (V double-buffer).
__device__ __forceinline__ f32x4 mfma16(bf16x8 a, bf16x8 b, f32x4 c) {
  return __builtin_amdgcn_mfma_f32_16x16x32_bf16(a, b, c, 0, 0, 0);
}

template <int CUR>
__device__ __forceinline__ void attn_iter(bool pref,
                                          bf16x8 (&kC)[4][2], bf16x8 (&kN)[4][2],
                                          const bf16x8 (&qf)[2][2],
                                          const u16* (&kp)[4], const u16*& vp,
                                          u16 (&Vt)[2][64 * 64],
                                          f32x4 (&oacc)[2][4], float (&l_i)[2],
                                          int chbase, int pcol, int l15, int colA, int colB) {
  // QK^T swapped: sacc[f][nt] = S^T tile, lane holds S[key=quad*4+r+16nt][qrow=l15]
  f32x4 sacc[2][4] = {};
#pragma unroll
  for (int nt = 0; nt < 4; ++nt) {
    bf16x8 k0 = kC[nt][0], k1 = kC[nt][1];
    sacc[0][nt] = mfma16(k0, qf[0][0], sacc[0][nt]);
    sacc[0][nt] = mfma16(k1, qf[0][1], sacc[0][nt]);
    sacc[1][nt] = mfma16(k0, qf[1][0], sacc[1][nt]);
    sacc[1][nt] = mfma16(k1, qf[1][1], sacc[1][nt]);
  }
  // prefetch K(kt+1) fragments and V(kt+1) rows into registers
  u16x8 va, vq;
  if (pref) {
#pragma unroll
    for (int nt = 0; nt < 4; ++nt) {
      kp[nt] += 64 * 2048;
      kN[nt][0] = *(const bf16x8*)kp[nt];
      kN[nt][1] = *(const bf16x8*)(kp[nt] + 32);
    }
    vp += 64 * 2048;
    va = *(const u16x8*)vp;
    vq = *(const u16x8*)(vp + 2048);
  }
  // softmax: p = 2^s (log2e folded into q gate); pack to bf16 in-register (zero cross-lane)
  u32 pw[2][8];
#pragma unroll
  for (int f = 0; f < 2; ++f) {
    float pe[4][4];
    float ls = 0.f;
#pragma unroll
    for (int nt = 0; nt < 4; ++nt) {
#pragma unroll
      for (int r = 0; r < 4; ++r) pe[nt][r] = __builtin_amdgcn_exp2f(sacc[f][nt][r]);
      ls += (pe[nt][0] + pe[nt][1]) + (pe[nt][2] + pe[nt][3]);
    }
    l_i[f] += ls;
    pw[f][0] = cvtpk(pe[0][0], pe[0][1]); pw[f][1] = cvtpk(pe[0][2], pe[0][3]);
    pw[f][2] = cvtpk(pe[1][0], pe[1][1]); pw[f][3] = cvtpk(pe[1][2], pe[1][3]);
    pw[f][4] = cvtpk(pe[2][0], pe[2][1]); pw[f][5] = cvtpk(pe[2][2], pe[2][3]);
    pw[f][6] = cvtpk(pe[3][0], pe[3][1]); pw[f][7] = cvtpk(pe[3][2], pe[3][3]);
  }
  union U8 { u32 w[4]; bf16x8 v; };
  bf16x8 pa[2][2];
#pragma unroll
  for (int f = 0; f < 2; ++f) {
    U8 t0; t0.w[0] = pw[f][0]; t0.w[1] = pw[f][1]; t0.w[2] = pw[f][2]; t0.w[3] = pw[f][3];
    U8 t1; t1.w[0] = pw[f][4]; t1.w[1] = pw[f][5]; t1.w[2] = pw[f][6]; t1.w[3] = pw[f][7];
    pa[f][0] = t0.v; pa[f][1] = t1.v;
  }
  // PV: V B-frags from swizzled, pi-permuted LDS
  const u16* vt0 = Vt[CUR];
#pragma unroll
  for (int nt = 0; nt < 4; ++nt) {
    const u16* vrow = vt0 + (nt * 16 + l15) * 64;
    bf16x8 vA = *(const bf16x8*)(vrow + colA);
    bf16x8 vB = *(const bf16x8*)(vrow + colB);
    oacc[0][nt] = mfma16(pa[0][0], vA, oacc[0][nt]);
    oacc[0][nt] = mfma16(pa[0][1], vB, oacc[0][nt]);
    oacc[1][nt] = mfma16(pa[1][0], vA, oacc[1][nt]);
    oacc[1][nt] = mfma16(pa[1][1], vB, oacc[1][nt]);
  }
  // stage V(kt+1) into other buffer (readers of it finished at previous barrier)
  if (pref) {
    u16* vd = (u16*)Vt[CUR ^ 1];
#pragma unroll
    for (int c = 0; c < 8; ++c) {
      u32 pk2 = (u32)va[c] | ((u32)vq[c] << 16);
      *(u32*)&vd[(chbase + c) * 64 + (pcol ^ (c << 3))] = pk2;
    }
  }
  __syncthreads();
}

__global__ __launch_bounds__(256, 2) void k_attn(const u16* __restrict__ qatt,
                                                 const u16* __restrict__ key,
                                                 const u16* __restrict__ value,
                                                 const float* __restrict__ hbuf,
                                                 float* __restrict__ out) {
  int bh = blockIdx.x & 31;
  int qt = blockIdx.x >> 5;
  int b = bh >> 4, h = bh & 15;
  int tid = threadIdx.x, wave = tid >> 6, lane = tid & 63;
  int l15 = lane & 15, quad = lane >> 4;
  int q0 = qt * 128;

  __shared__ __align__(16) u16 Vt[2][64 * 64];   // [buf][ch][pi(key)], XOR-swizzled rows (128B)

  // Q B-frags: frag f covers queries q0 + f*64 + wave*16 + [0,16); lane holds Q[qrow=l15][ch=quad*8..]
  bf16x8 qf[2][2];
#pragma unroll
  for (int f = 0; f < 2; ++f) {
    const u16* qrow = qatt + ((size_t)bh * 2048 + q0 + f * 64 + wave * 16 + l15) * 64 + quad * 8;
    qf[f][0] = *(const bf16x8*)qrow;
    qf[f][1] = *(const bf16x8*)(qrow + 32);
  }

  const u16* kb = key + (size_t)b * 1024 + (size_t)h * 64;
  const u16* vb = value + (size_t)b * 1024 + (size_t)h * 64;

  // K A-frag pointers: lane holds K[key=nt*16+l15][ch=quad*8..+7] (+32 via imm offset)
  const u16* kp[4];
#pragma unroll
  for (int nt = 0; nt < 4; ++nt) kp[nt] = kb + (size_t)(nt * 16 + l15) * 2048 + quad * 8;

  // V staging: lane covers keys 2p,2p+1 (p=lane&31), 8 ch at chbase; scatter col = pi(2p)
  int p = lane & 31;
  int chbase = wave * 16 + (lane >> 5) * 8;
  const u16* vp = vb + (size_t)2 * p * 2048 + chbase;
  int kk = 2 * p;
  int pcol = ((kk >> 5) & 1) * 32 + ((kk >> 2) & 3) * 8 + ((kk >> 4) & 1) * 4 + (kk & 3);
  int swr = (l15 & 7) << 3;            // read-side row swizzle (u16 units)
  int colA = (8 * quad) ^ swr;
  int colB = (32 + 8 * quad) ^ swr;

  // prologue: K(0) frags into regs, V(0) into Vt[0]
  bf16x8 kA[4][2], kB[4][2];
#pragma unroll
  for (int nt = 0; nt < 4; ++nt) {
    kA[nt][0] = *(const bf16x8*)kp[nt];
    kA[nt][1] = *(const bf16x8*)(kp[nt] + 32);
  }
  {
    u16x8 va = *(const u16x8*)vp;
    u16x8 vq = *(const u16x8*)(vp + 2048);
#pragma unroll
    for (int c = 0; c < 8; ++c) {
      u32 pk2 = (u32)va[c] | ((u32)vq[c] << 16);
      *(u32*)&Vt[0][(chbase + c) * 64 + (pcol ^ (c << 3))] = pk2;
    }
  }
  __syncthreads();

  f32x4 oacc[2][4] = {};
  float l_i[2] = {};

  for (int kt = 0; kt < 32; kt += 2) {
    attn_iter<0>(true, kA, kB, qf, kp, vp, Vt, oacc, l_i, chbase, pcol, l15, colA, colB);
    attn_iter<1>(kt < 30, kB, kA, qf, kp, vp, Vt, oacc, l_i, chbase, pcol, l15, colA, colB);
  }

  // l reduction: lane holds partial for qrow=l15; sum across quads
#pragma unroll
  for (int f = 0; f < 2; ++f) {
    float l = l_i[f];
    l += __shfl_xor(l, 16);
    l += __shfl_xor(l, 32);
    l_i[f] = l;
  }
  // vsig inline (h holds MLP pre-activations: c = h[ch], f = h[1024+ch])
  float vsg[4];
#pragma unroll
  for (int nt = 0; nt < 4; ++nt) {
    int ch = h * 64 + nt * 16 + l15;
    vsg[nt] = sigm(hbuf[1024 + ch]) * tanhf(hbuf[ch]);
  }
  // epilogue: oacc[f][nt][r] = O[qrow=quad*4+r (+f*16)][ch=nt*16+l15]; /l, *vsig, write (s,b,H) fp32
#pragma unroll
  for (int f = 0; f < 2; ++f)
#pragma unroll
    for (int r = 0; r < 4; ++r) {
      int sq = q0 + f * 64 + wave * 16 + quad * 4 + r;
      float inv = 1.0f / __shfl(l_i[f], quad * 4 + r);
      float* orow = out + ((size_t)sq * 2 + b) * 1024 + h * 64;
#pragma unroll
      for (int nt = 0; nt < 4; ++nt)
        orow[nt * 16 + l15] = oacc[f][nt][r] * inv * vsg[nt];
    }
}

extern "C" void kernel_launch(void* const* d_in, const int* in_sizes, int n_in,
                              void* d_out, int out_size, void* d_ws, size_t ws_size,
                              hipStream_t stream) {
  (void)in_sizes; (void)n_in; (void)out_size; (void)ws_size;
  const float* query = (const float*)d_in[0];
  const float* key   = (const float*)d_in[1];
  const float* value = (const float*)d_in[2];
  const float* qs    = (const float*)d_in[3];
  const float* ksp   = (const float*)d_in[4];
  const float* vs    = (const float*)d_in[5];
  const float* vq_w  = (const float*)d_in[6];
  const float* vq_b  = (const float*)d_in[7];
  const float* ql_w  = (const float*)d_in[8];
  const float* ql_b  = (const float*)d_in[9];
  const float* ln_g  = (const float*)d_in[10];
  const float* ln_b  = (const float*)d_in[11];
  float* out = (float*)d_out;

  float* ws = (float*)d_ws;
  float* h   = ws;                                  // 2048 f32
  u16* qpre  = (u16*)(ws + 4096);                   // 2 x 4096x1024 bf16 (16 MB)
  u16* qbf   = qpre + (size_t)2 * 4096 * 1024;      // query bf16 (16 MB); qatt aliases
  u16* qatt  = qbf;                                 // 32x2048x64 bf16 (ln writes after gemm reads)
  u16* wbf   = qbf + (size_t)4096 * 2048;           // ql_w bf16 (4 MB)
  u16* kbf   = wbf + (size_t)1024 * 2048;           // key bf16 (8 MB)
  u16* vbf   = kbf + (size_t)4096 * 1024;           // value bf16 (8 MB)

  hipLaunchKernelGGL(k_cvt_all, dim3(18432), dim3(256), 0, stream,
                     (const float4*)query, (u16x4*)qbf,
                     (const float4*)ql_w,  (u16x4*)wbf,
                     (const float4*)key,   (u16x4*)kbf,
                     (const float4*)value, (u16x4*)vbf);
  hipLaunchKernelGGL(k_h,    dim3(512),  dim3(256), 0, stream, vs, vq_w, vq_b, h);
  hipLaunchKernelGGL(k_gemm, dim3(512),  dim3(256), 0, stream, qbf, wbf, qpre);
  hipLaunchKernelGGL(k_ln,   dim3(4096), dim3(256), 0, stream, qpre, qpre + (size_t)4096 * 1024,
                     ql_b, ln_g, ln_b, qs, ksp, qatt);
  hipLaunchKernelGGL(k_attn, dim3(512),  dim3(256), 0, stream, qatt, kbf, vbf, h, out);
}

// Round 2
// 221.995 us; speedup vs baseline: 1.1639x; 1.1639x over previous
//
#include <hip/hip_runtime.h>

typedef __bf16 bf16x8 __attribute__((ext_vector_type(8)));
typedef float f32x4 __attribute__((ext_vector_type(4)));
typedef unsigned short u16x8 __attribute__((ext_vector_type(8)));
typedef unsigned short u16x4 __attribute__((ext_vector_type(4)));
typedef unsigned short u16;
typedef unsigned int u32;

// S=2048, B=2, H=1024, NH=16, HD=64, SCALE=32 (exact)
// Inputs fp32, output fp32. Internal: bf16 MFMA, fp32 accum.
// Softmax is max-free (scores tightly bounded); log2(e) folded into q gate -> exp2 direct.

#define LOG2E 1.4426950408889634f

__device__ __forceinline__ float b2f(u16 u) {
  union { unsigned int i; float f; } x; x.i = ((unsigned int)u) << 16; return x.f;
}
__device__ __forceinline__ u16 f2b(float f) {
  union { float f; unsigned int i; } x; x.f = f;
  unsigned int r = (x.i + 0x7fffu + ((x.i >> 16) & 1u)) >> 16;
  return (u16)r;
}
__device__ __forceinline__ float sigm(float x) { return 1.0f / (1.0f + __expf(-x)); }
__device__ __forceinline__ u32 cvtpk(float lo, float hi) {
  u32 r; asm("v_cvt_pk_bf16_f32 %0, %1, %2" : "=v"(r) : "v"(lo), "v"(hi)); return r;
}

__device__ __forceinline__ void async16(u16* lds, const u16* g) {
  __builtin_amdgcn_global_load_lds((const __attribute__((address_space(1))) void*)g,
                                   (__attribute__((address_space(3))) void*)lds, 16, 0, 0);
}

// ---- kernel 0: all fp32->bf16 conversions in one launch (grid 18432)
__global__ __launch_bounds__(256) void k_cvt_all(const float4* __restrict__ q, u16x4* __restrict__ qd,
                                                 const float4* __restrict__ w, u16x4* __restrict__ wd,
                                                 const float4* __restrict__ k, u16x4* __restrict__ kd,
                                                 const float4* __restrict__ v, u16x4* __restrict__ vd) {
  int b = blockIdx.x;
  const float4* s; u16x4* d; int i;
  if (b < 8192)       { s = q; d = qd; i = b * 256 + threadIdx.x; }
  else if (b < 10240) { s = w; d = wd; i = (b - 8192) * 256 + threadIdx.x; }
  else if (b < 14336) { s = k; d = kd; i = (b - 10240) * 256 + threadIdx.x; }
  else                { s = v; d = vd; i = (b - 14336) * 256 + threadIdx.x; }
  float4 x = s[i];
  u16x4 o; o[0] = f2b(x.x); o[1] = f2b(x.y); o[2] = f2b(x.z); o[3] = f2b(x.w);
  d[i] = o;
}

// ---- kernel 1: h = sigmoid(vs) @ vq_w.T + vq_b   (wave per row, 512 blocks)
__global__ __launch_bounds__(256) void k_h(const float* __restrict__ vs,
                                           const float* __restrict__ vq_w,
                                           const float* __restrict__ vq_b,
                                           float* __restrict__ h) {
  __shared__ float svs[1024];
  int t = threadIdx.x;
  for (int i = t; i < 1024; i += 256) svs[i] = sigm(vs[i]);
  __syncthreads();
  int wave = t >> 6, lane = t & 63;
  int row = blockIdx.x * 4 + wave;
  const float4* w4 = (const float4*)(vq_w + (size_t)row * 1024);
  const float4* s4 = (const float4*)svs;
  float acc = 0.f;
#pragma unroll
  for (int k = 0; k < 4; ++k) {
    float4 w = w4[k * 64 + lane];
    float4 s = s4[k * 64 + lane];
    acc += w.x * s.x + w.y * s.y + w.z * s.z + w.w * s.w;
  }
#pragma unroll
  for (int off = 1; off < 64; off <<= 1) acc += __shfl_xor(acc, off);
  if (lane == 0) h[row] = acc + vq_b[row];
}

// ---- kernel 3: qpre = query @ ql_w^T, split-K=2 (grid 512: kh = bx>>8)
__global__ __launch_bounds__(256) void k_gemm(const u16* __restrict__ A,    // 4096 x 2048 bf16
                                              const u16* __restrict__ Bt,   // 1024 x 2048 bf16
                                              u16* __restrict__ C) {        // 2 x (4096 x 1024)
  __shared__ __align__(16) u16 As[128 * 32];
  __shared__ __align__(16) u16 Bs[128 * 32];
  int tid = threadIdx.x;
  int wave = tid >> 6, lane = tid & 63;
  int l15 = lane & 15, quad = lane >> 4;
  int bx = blockIdx.x & 255;
  int kh = blockIdx.x >> 8;
  int kofs = kh << 10;
  int m0 = (bx >> 3) * 128;
  int n0 = (bx & 7) * 128;
  int wm = (wave >> 1) * 64, wn = (wave & 1) * 64;
  f32x4 acc[4][4] = {};
  int c1 = tid, c2 = tid + 256;
  const u16* ga1 = A + (size_t)(m0 + (c1 >> 2)) * 2048 + kofs + (c1 & 3) * 8;
  const u16* ga2 = A + (size_t)(m0 + (c2 >> 2)) * 2048 + kofs + (c2 & 3) * 8;
  const u16* gb1 = Bt + (size_t)(n0 + (c1 >> 2)) * 2048 + kofs + (c1 & 3) * 8;
  const u16* gb2 = Bt + (size_t)(n0 + (c2 >> 2)) * 2048 + kofs + (c2 & 3) * 8;
  u16* lA1 = As + wave * 512;
  u16* lA2 = As + 2048 + wave * 512;
  u16* lB1 = Bs + wave * 512;
  u16* lB2 = Bs + 2048 + wave * 512;
  for (int kt = 0; kt < 32; ++kt) {
    async16(lA1, ga1); async16(lA2, ga2);
    async16(lB1, gb1); async16(lB2, gb2);
    ga1 += 32; ga2 += 32; gb1 += 32; gb2 += 32;
    __syncthreads();
    bf16x8 af[4], bfr[4];
#pragma unroll
    for (int mt = 0; mt < 4; ++mt)
      af[mt] = *(const bf16x8*)(As + (wm + mt * 16 + l15) * 32 + quad * 8);
#pragma unroll
    for (int nt = 0; nt < 4; ++nt)
      bfr[nt] = *(const bf16x8*)(Bs + (wn + nt * 16 + l15) * 32 + quad * 8);
#pragma unroll
    for (int mt = 0; mt < 4; ++mt)
#pragma unroll
      for (int nt = 0; nt < 4; ++nt)
        acc[mt][nt] = __builtin_amdgcn_mfma_f32_16x16x32_bf16(af[mt], bfr[nt], acc[mt][nt], 0, 0, 0);
    __syncthreads();
  }
  u16* Cp = C + (size_t)kh * 4096 * 1024;
#pragma unroll
  for (int mt = 0; mt < 4; ++mt) {
#pragma unroll
    for (int r = 0; r < 4; ++r) {
      int m = m0 + wm + mt * 16 + quad * 4 + r;
      u16* crow = Cp + (size_t)m * 1024 + n0 + wn + l15;
#pragma unroll
      for (int nt = 0; nt < 4; ++nt) crow[nt * 16] = f2b(acc[mt][nt][r]);
    }
  }
}

// ---- kernel 4: LN((qpre0+qpre1)+ql_b)*ln_g+ln_b, * sigm(qs)*sigm(ks)*log2e/32 -> qatt (b,h,s,hd)
__global__ __launch_bounds__(256) void k_ln(const u16* __restrict__ qpre0,
                                            const u16* __restrict__ qpre1,
                                            const float* __restrict__ ql_b,
                                            const float* __restrict__ ln_g,
                                            const float* __restrict__ ln_b,
                                            const float* __restrict__ qs,
                                            const float* __restrict__ ks,
                                            u16* __restrict__ qatt) {
  int row = blockIdx.x;   // row = s*2 + b
  int t = threadIdx.x;
  u16x4 a4 = *(const u16x4*)(qpre0 + (size_t)row * 1024 + t * 4);
  u16x4 b4 = *(const u16x4*)(qpre1 + (size_t)row * 1024 + t * 4);
  float v[4];
  float s = 0.f, ss = 0.f;
#pragma unroll
  for (int j = 0; j < 4; ++j) {
    v[j] = b2f(a4[j]) + b2f(b4[j]) + ql_b[t * 4 + j];
    s += v[j]; ss += v[j] * v[j];
  }
#pragma unroll
  for (int off = 1; off < 64; off <<= 1) { s += __shfl_xor(s, off); ss += __shfl_xor(ss, off); }
  __shared__ float red[8];
  int wv = t >> 6, ln = t & 63;
  if (ln == 0) { red[wv] = s; red[4 + wv] = ss; }
  __syncthreads();
  s = red[0] + red[1] + red[2] + red[3];
  ss = red[4] + red[5] + red[6] + red[7];
  float mu = s * (1.f / 1024.f);
  float rstd = rsqrtf(ss * (1.f / 1024.f) - mu * mu + 1e-12f);
  int sidx = row >> 1, b = row & 1;
  int ch0 = t * 4;
  int hh = ch0 >> 6, hd0 = ch0 & 63;
  u16* dst = qatt + ((size_t)(b * 16 + hh) * 2048 + sidx) * 64 + hd0;
#pragma unroll
  for (int j = 0; j < 4; ++j) {
    int ch = ch0 + j;
    float gate = sigm(qs[ch]) * sigm(ks[ch]) * (LOG2E / 32.0f);
    float y = (v[j] - mu) * rstd * ln_g[ch] + ln_b[ch];
    dst[j] = f2b(y * gate);
  }
}

// ---- kernel 5: flash attention, swapped-QK in-register softmax + LDS-staged K/V.
// mfma(K,Q) puts P[qrow=l15][16 keys] per lane == PV A-operand layout -> no P LDS round-trip.
// K staged cooperatively (8KB/iter, 2 coalesced 16B loads/thread) into XOR-swizzled [key][ch] LDS;
// A-frag read pattern is index-identical to the V read that measured 0 bank conflicts.
// V staged [ch][pi(key)] (pi matches P's key slot order), XOR-swizzled rows.
// grid 512: bh = bx & 31 (XCD L2 locality), qt = bx>>5. One barrier/iter (double-buffered).
__device__ __forceinline__ f32x4 mfma16(bf16x8 a, bf16x8 b, f32x4 c) {
  return __builtin_amdgcn_mfma_f32_16x16x32_bf16(a, b, c, 0, 0, 0);
}

template <int CUR>
__device__ __forceinline__ void attn_iter(bool pref,
                                          const bf16x8 (&qf)[2][2],
                                          const u16*& kp, const u16*& vp,
                                          u16 (&Ks)[2][64 * 64], u16 (&Vt)[2][64 * 64],
                                          f32x4 (&oacc)[2][4], float (&l_i)[2],
                                          int kdst, int chbase, int pcol,
                                          int l15, int colA, int colB) {
  // QK^T swapped: K A-frags from swizzled LDS. sacc[f][nt]: lane = S[key=quad*4+r+16nt][qrow=l15]
  f32x4 sacc[2][4] = {};
  const u16* kt0 = Ks[CUR];
#pragma unroll
  for (int nt = 0; nt < 4; ++nt) {
    const u16* krow = kt0 + (nt * 16 + l15) * 64;
    bf16x8 kA = *(const bf16x8*)(krow + colA);
    bf16x8 kB = *(const bf16x8*)(krow + colB);
    sacc[0][nt] = mfma16(kA, qf[0][0], sacc[0][nt]);
    sacc[0][nt] = mfma16(kB, qf[0][1], sacc[0][nt]);
    sacc[1][nt] = mfma16(kA, qf[1][0], sacc[1][nt]);
    sacc[1][nt] = mfma16(kB, qf[1][1], sacc[1][nt]);
  }
  // prefetch K(kt+1), V(kt+1) rows into registers (coalesced, 2+2 x 16B per thread)
  u16x8 kr0, kr1, va, vq;
  if (pref) {
    kp += 64 * 2048;
    kr0 = *(const u16x8*)kp;
    kr1 = *(const u16x8*)(kp + (size_t)32 * 2048);
    vp += 64 * 2048;
    va = *(const u16x8*)vp;
    vq = *(const u16x8*)(vp + 2048);
  }
  // softmax: p = 2^s (log2e folded into q gate); pack to bf16 in-register (zero cross-lane)
  u32 pw[2][8];
#pragma unroll
  for (int f = 0; f < 2; ++f) {
    float pe[4][4];
    float ls = 0.f;
#pragma unroll
    for (int nt = 0; nt < 4; ++nt) {
#pragma unroll
      for (int r = 0; r < 4; ++r) pe[nt][r] = __builtin_amdgcn_exp2f(sacc[f][nt][r]);
      ls += (pe[nt][0] + pe[nt][1]) + (pe[nt][2] + pe[nt][3]);
    }
    l_i[f] += ls;
    pw[f][0] = cvtpk(pe[0][0], pe[0][1]); pw[f][1] = cvtpk(pe[0][2], pe[0][3]);
    pw[f][2] = cvtpk(pe[1][0], pe[1][1]); pw[f][3] = cvtpk(pe[1][2], pe[1][3]);
    pw[f][4] = cvtpk(pe[2][0], pe[2][1]); pw[f][5] = cvtpk(pe[2][2], pe[2][3]);
    pw[f][6] = cvtpk(pe[3][0], pe[3][1]); pw[f][7] = cvtpk(pe[3][2], pe[3][3]);
  }
  union U8 { u32 w[4]; bf16x8 v; };
  bf16x8 pa[2][2];
#pragma unroll
  for (int f = 0; f < 2; ++f) {
    U8 t0; t0.w[0] = pw[f][0]; t0.w[1] = pw[f][1]; t0.w[2] = pw[f][2]; t0.w[3] = pw[f][3];
    U8 t1; t1.w[0] = pw[f][4]; t1.w[1] = pw[f][5]; t1.w[2] = pw[f][6]; t1.w[3] = pw[f][7];
    pa[f][0] = t0.v; pa[f][1] = t1.v;
  }
  // PV: V B-frags from swizzled, pi-permuted LDS
  const u16* vt0 = Vt[CUR];
#pragma unroll
  for (int nt = 0; nt < 4; ++nt) {
    const u16* vrow = vt0 + (nt * 16 + l15) * 64;
    bf16x8 vA = *(const bf16x8*)(vrow + colA);
    bf16x8 vB = *(const bf16x8*)(vrow + colB);
    oacc[0][nt] = mfma16(pa[0][0], vA, oacc[0][nt]);
    oacc[0][nt] = mfma16(pa[0][1], vB, oacc[0][nt]);
    oacc[1][nt] = mfma16(pa[1][0], vA, oacc[1][nt]);
    oacc[1][nt] = mfma16(pa[1][1], vB, oacc[1][nt]);
  }
  // stage K(kt+1), V(kt+1) into other buffer (readers finished at previous barrier)
  if (pref) {
    u16* kd = (u16*)Ks[CUR ^ 1];
    *(u16x8*)(kd + kdst) = kr0;
    *(u16x8*)(kd + kdst + 2048) = kr1;
    u16* vd = (u16*)Vt[CUR ^ 1];
#pragma unroll
    for (int c = 0; c < 8; ++c) {
      u32 pk2 = (u32)va[c] | ((u32)vq[c] << 16);
      *(u32*)&vd[(chbase + c) * 64 + (pcol ^ (c << 3))] = pk2;
    }
  }
  __syncthreads();
}

__global__ __launch_bounds__(256, 2) void k_attn(const u16* __restrict__ qatt,
                                                 const u16* __restrict__ key,
                                                 const u16* __restrict__ value,
                                                 const float* __restrict__ hbuf,
                                                 float* __restrict__ out) {
  int bh = blockIdx.x & 31;
  int qt = blockIdx.x >> 5;
  int b = bh >> 4, h = bh & 15;
  int tid = threadIdx.x, wave = tid >> 6, lane = tid & 63;
  int l15 = lane & 15, quad = lane >> 4;
  int q0 = qt * 128;

  __shared__ __align__(16) u16 Ks[2][64 * 64];   // [buf][key][ch], XOR-swizzled 128B rows
  __shared__ __align__(16) u16 Vt[2][64 * 64];   // [buf][ch][pi(key)], XOR-swizzled 128B rows

  // Q B-frags: frag f covers queries q0 + f*64 + wave*16 + [0,16); lane holds Q[qrow=l15][ch=quad*8..]
  bf16x8 qf[2][2];
#pragma unroll
  for (int f = 0; f < 2; ++f) {
    const u16* qrow = qatt + ((size_t)bh * 2048 + q0 + f * 64 + wave * 16 + l15) * 64 + quad * 8;
    qf[f][0] = *(const bf16x8*)qrow;
    qf[f][1] = *(const bf16x8*)(qrow + 32);
  }

  const u16* kb = key + (size_t)b * 1024 + (size_t)h * 64;
  const u16* vb = value + (size_t)b * 1024 + (size_t)h * 64;

  // K staging: thread t covers rows {t>>3, 32+(t>>3)}, ch chunk (t&7)*8 (128B row segments, coalesced)
  int krow = tid >> 3;
  int kchk = (tid & 7) * 8;
  const u16* kp = kb + (size_t)krow * 2048 + kchk;
  int kdst = krow * 64 + (kchk ^ ((krow & 7) << 3));   // +2048 for row+32 (same &7)

  // V staging: lane covers keys 2p,2p+1 (p=lane&31), 8 ch at chbase; scatter col = pi(2p)
  int p = lane & 31;
  int chbase = wave * 16 + (lane >> 5) * 8;
  const u16* vp = vb + (size_t)2 * p * 2048 + chbase;
  int kk = 2 * p;
  int pcol = ((kk >> 5) & 1) * 32 + ((kk >> 2) & 3) * 8 + ((kk >> 4) & 1) * 4 + (kk & 3);
  int swr = (l15 & 7) << 3;            // read-side row swizzle (u16 units)
  int colA = (8 * quad) ^ swr;
  int colB = (32 + 8 * quad) ^ swr;

  // prologue: K(0) into Ks[0], V(0) into Vt[0]
  {
    u16x8 kr0 = *(const u16x8*)kp;
    u16x8 kr1 = *(const u16x8*)(kp + (size_t)32 * 2048);
    *(u16x8*)(&Ks[0][kdst]) = kr0;
    *(u16x8*)(&Ks[0][kdst + 2048]) = kr1;
    u16x8 va = *(const u16x8*)vp;
    u16x8 vq = *(const u16x8*)(vp + 2048);
#pragma unroll
    for (int c = 0; c < 8; ++c) {
      u32 pk2 = (u32)va[c] | ((u32)vq[c] << 16);
      *(u32*)&Vt[0][(chbase + c) * 64 + (pcol ^ (c << 3))] = pk2;
    }
  }
  __syncthreads();

  f32x4 oacc[2][4] = {};
  float l_i[2] = {};

  for (int kt = 0; kt < 32; kt += 2) {
    attn_iter<0>(true, qf, kp, vp, Ks, Vt, oacc, l_i, kdst, chbase, pcol, l15, colA, colB);
    attn_iter<1>(kt < 30, qf, kp, vp, Ks, Vt, oacc, l_i, kdst, chbase, pcol, l15, colA, colB);
  }

  // l reduction: lane holds partial for qrow=l15; sum across quads
#pragma unroll
  for (int f = 0; f < 2; ++f) {
    float l = l_i[f];
    l += __shfl_xor(l, 16);
    l += __shfl_xor(l, 32);
    l_i[f] = l;
  }
  // vsig inline (h holds MLP pre-activations: c = h[ch], f = h[1024+ch])
  float vsg[4];
#pragma unroll
  for (int nt = 0; nt < 4; ++nt) {
    int ch = h * 64 + nt * 16 + l15;
    vsg[nt] = sigm(hbuf[1024 + ch]) * tanhf(hbuf[ch]);
  }
  // epilogue: oacc[f][nt][r] = O[qrow=quad*4+r (+f*16)][ch=nt*16+l15]; /l, *vsig, write (s,b,H) fp32
#pragma unroll
  for (int f = 0; f < 2; ++f)
#pragma unroll
    for (int r = 0; r < 4; ++r) {
      int sq = q0 + f * 64 + wave * 16 + quad * 4 + r;
      float inv = 1.0f / __shfl(l_i[f], quad * 4 + r);
      float* orow = out + ((size_t)sq * 2 + b) * 1024 + h * 64;
#pragma unroll
      for (int nt = 0; nt < 4; ++nt)
        orow[nt * 16 + l15] = oacc[f][nt][r] * inv * vsg[nt];
    }
}

extern "C" void kernel_launch(void* const* d_in, const int* in_sizes, int n_in,
                              void* d_out, int out_size, void* d_ws, size_t ws_size,
                              hipStream_t stream) {
  (void)in_sizes; (void)n_in; (void)out_size; (void)ws_size;
  const float* query = (const float*)d_in[0];
  const float* key   = (const float*)d_in[1];
  const float* value = (const float*)d_in[2];
  const float* qs    = (const float*)d_in[3];
  const float* ksp   = (const float*)d_in[4];
  const float* vs    = (const float*)d_in[5];
  const float* vq_w  = (const float*)d_in[6];
  const float* vq_b  = (const float*)d_in[7];
  const float* ql_w  = (const float*)d_in[8];
  const float* ql_b  = (const float*)d_in[9];
  const float* ln_g  = (const float*)d_in[10];
  const float* ln_b  = (const float*)d_in[11];
  float* out = (float*)d_out;

  float* ws = (float*)d_ws;
  float* h   = ws;                                  // 2048 f32
  u16* qpre  = (u16*)(ws + 4096);                   // 2 x 4096x1024 bf16 (16 MB)
  u16* qbf   = qpre + (size_t)2 * 4096 * 1024;      // query bf16 (16 MB); qatt aliases
  u16* qatt  = qbf;                                 // 32x2048x64 bf16 (ln writes after gemm reads)
  u16* wbf   = qbf + (size_t)4096 * 2048;           // ql_w bf16 (4 MB)
  u16* kbf   = wbf + (size_t)1024 * 2048;           // key bf16 (8 MB)
  u16* vbf   = kbf + (size_t)4096 * 1024;           // value bf16 (8 MB)

  hipLaunchKernelGGL(k_cvt_all, dim3(18432), dim3(256), 0, stream,
                     (const float4*)query, (u16x4*)qbf,
                     (const float4*)ql_w,  (u16x4*)wbf,
                     (const float4*)key,   (u16x4*)kbf,
                     (const float4*)value, (u16x4*)vbf);
  hipLaunchKernelGGL(k_h,    dim3(512),  dim3(256), 0, stream, vs, vq_w, vq_b, h);
  hipLaunchKernelGGL(k_gemm, dim3(512),  dim3(256), 0, stream, qbf, wbf, qpre);
  hipLaunchKernelGGL(k_ln,   dim3(4096), dim3(256), 0, stream, qpre, qpre + (size_t)4096 * 1024,
                     ql_b, ln_g, ln_b, qs, ksp, qatt);
  hipLaunchKernelGGL(k_attn, dim3(512),  dim3(256), 0, stream, qatt, kbf, vbf, h, out);
}

// Round 3
// 220.091 us; speedup vs baseline: 1.1740x; 1.0087x over previous
//
#include <hip/hip_runtime.h>

typedef __bf16 bf16x8 __attribute__((ext_vector_type(8)));
typedef float f32x4 __attribute__((ext_vector_type(4)));
typedef unsigned short u16x8 __attribute__((ext_vector_type(8)));
typedef unsigned short u16x4 __attribute__((ext_vector_type(4)));
typedef unsigned short u16;
typedef unsigned int u32;

// S=2048, B=2, H=1024, NH=16, HD=64, SCALE=32 (exact)
// Inputs fp32, output fp32. Internal: bf16 MFMA, fp32 accum.
// Softmax is max-free (scores tightly bounded); log2(e) folded into q gate -> exp2 direct.

#define LOG2E 1.4426950408889634f

__device__ __forceinline__ float b2f(u16 u) {
  union { unsigned int i; float f; } x; x.i = ((unsigned int)u) << 16; return x.f;
}
__device__ __forceinline__ u16 f2b(float f) {
  union { float f; unsigned int i; } x; x.f = f;
  unsigned int r = (x.i + 0x7fffu + ((x.i >> 16) & 1u)) >> 16;
  return (u16)r;
}
__device__ __forceinline__ float sigm(float x) { return 1.0f / (1.0f + __expf(-x)); }
__device__ __forceinline__ u32 cvtpk(float lo, float hi) {
  u32 r; asm("v_cvt_pk_bf16_f32 %0, %1, %2" : "=v"(r) : "v"(lo), "v"(hi)); return r;
}

__device__ __forceinline__ void async16(u16* lds, const u16* g) {
  __builtin_amdgcn_global_load_lds((const __attribute__((address_space(1))) void*)g,
                                   (__attribute__((address_space(3))) void*)lds, 16, 0, 0);
}

// ---- kernel 0: all fp32->bf16 conversions + h MLP in one launch (grid 18944)
__global__ __launch_bounds__(256) void k_cvt_h(const float4* __restrict__ q, u16x4* __restrict__ qd,
                                               const float4* __restrict__ w, u16x4* __restrict__ wd,
                                               const float4* __restrict__ k, u16x4* __restrict__ kd,
                                               const float4* __restrict__ v, u16x4* __restrict__ vd,
                                               const float* __restrict__ vs,
                                               const float* __restrict__ vq_w,
                                               const float* __restrict__ vq_b,
                                               float* __restrict__ h) {
  __shared__ float svs[1024];
  int b = blockIdx.x;
  int t = threadIdx.x;
  if (b >= 18432) {
    // h = sigmoid(vs) @ vq_w.T + vq_b  (wave per row, blocks 18432..18943)
    for (int i = t; i < 1024; i += 256) svs[i] = sigm(vs[i]);
    __syncthreads();
    int wave = t >> 6, lane = t & 63;
    int row = (b - 18432) * 4 + wave;
    const float4* w4 = (const float4*)(vq_w + (size_t)row * 1024);
    const float4* s4 = (const float4*)svs;
    float acc = 0.f;
#pragma unroll
    for (int kk = 0; kk < 4; ++kk) {
      float4 wv = w4[kk * 64 + lane];
      float4 sv = s4[kk * 64 + lane];
      acc += wv.x * sv.x + wv.y * sv.y + wv.z * sv.z + wv.w * sv.w;
    }
#pragma unroll
    for (int off = 1; off < 64; off <<= 1) acc += __shfl_xor(acc, off);
    if (lane == 0) h[row] = acc + vq_b[row];
    return;
  }
  const float4* s; u16x4* d; int i;
  if (b < 8192)       { s = q; d = qd; i = b * 256 + t; }
  else if (b < 10240) { s = w; d = wd; i = (b - 8192) * 256 + t; }
  else if (b < 14336) { s = k; d = kd; i = (b - 10240) * 256 + t; }
  else                { s = v; d = vd; i = (b - 14336) * 256 + t; }
  float4 x = s[i];
  u16x4 o; o[0] = f2b(x.x); o[1] = f2b(x.y); o[2] = f2b(x.z); o[3] = f2b(x.w);
  d[i] = o;
}

// ---- kernel 3: qpre = query @ ql_w^T, split-K=2 (grid 512: kh = bx>>8)
__global__ __launch_bounds__(256) void k_gemm(const u16* __restrict__ A,    // 4096 x 2048 bf16
                                              const u16* __restrict__ Bt,   // 1024 x 2048 bf16
                                              u16* __restrict__ C) {        // 2 x (4096 x 1024)
  __shared__ __align__(16) u16 As[128 * 32];
  __shared__ __align__(16) u16 Bs[128 * 32];
  int tid = threadIdx.x;
  int wave = tid >> 6, lane = tid & 63;
  int l15 = lane & 15, quad = lane >> 4;
  int bx = blockIdx.x & 255;
  int kh = blockIdx.x >> 8;
  int kofs = kh << 10;
  int m0 = (bx >> 3) * 128;
  int n0 = (bx & 7) * 128;
  int wm = (wave >> 1) * 64, wn = (wave & 1) * 64;
  f32x4 acc[4][4] = {};
  int c1 = tid, c2 = tid + 256;
  const u16* ga1 = A + (size_t)(m0 + (c1 >> 2)) * 2048 + kofs + (c1 & 3) * 8;
  const u16* ga2 = A + (size_t)(m0 + (c2 >> 2)) * 2048 + kofs + (c2 & 3) * 8;
  const u16* gb1 = Bt + (size_t)(n0 + (c1 >> 2)) * 2048 + kofs + (c1 & 3) * 8;
  const u16* gb2 = Bt + (size_t)(n0 + (c2 >> 2)) * 2048 + kofs + (c2 & 3) * 8;
  u16* lA1 = As + wave * 512;
  u16* lA2 = As + 2048 + wave * 512;
  u16* lB1 = Bs + wave * 512;
  u16* lB2 = Bs + 2048 + wave * 512;
  for (int kt = 0; kt < 32; ++kt) {
    async16(lA1, ga1); async16(lA2, ga2);
    async16(lB1, gb1); async16(lB2, gb2);
    ga1 += 32; ga2 += 32; gb1 += 32; gb2 += 32;
    __syncthreads();
    bf16x8 af[4], bfr[4];
#pragma unroll
    for (int mt = 0; mt < 4; ++mt)
      af[mt] = *(const bf16x8*)(As + (wm + mt * 16 + l15) * 32 + quad * 8);
#pragma unroll
    for (int nt = 0; nt < 4; ++nt)
      bfr[nt] = *(const bf16x8*)(Bs + (wn + nt * 16 + l15) * 32 + quad * 8);
#pragma unroll
    for (int mt = 0; mt < 4; ++mt)
#pragma unroll
      for (int nt = 0; nt < 4; ++nt)
        acc[mt][nt] = __builtin_amdgcn_mfma_f32_16x16x32_bf16(af[mt], bfr[nt], acc[mt][nt], 0, 0, 0);
    __syncthreads();
  }
  u16* Cp = C + (size_t)kh * 4096 * 1024;
#pragma unroll
  for (int mt = 0; mt < 4; ++mt) {
#pragma unroll
    for (int r = 0; r < 4; ++r) {
      int m = m0 + wm + mt * 16 + quad * 4 + r;
      u16* crow = Cp + (size_t)m * 1024 + n0 + wn + l15;
#pragma unroll
      for (int nt = 0; nt < 4; ++nt) crow[nt * 16] = f2b(acc[mt][nt][r]);
    }
  }
}

// ---- kernel 4: LN((qpre0+qpre1)+ql_b)*ln_g+ln_b, * sigm(qs)*sigm(ks)*log2e/32 -> qatt (b,h,s,hd)
__global__ __launch_bounds__(256) void k_ln(const u16* __restrict__ qpre0,
                                            const u16* __restrict__ qpre1,
                                            const float* __restrict__ ql_b,
                                            const float* __restrict__ ln_g,
                                            const float* __restrict__ ln_b,
                                            const float* __restrict__ qs,
                                            const float* __restrict__ ks,
                                            u16* __restrict__ qatt) {
  int row = blockIdx.x;   // row = s*2 + b
  int t = threadIdx.x;
  u16x4 a4 = *(const u16x4*)(qpre0 + (size_t)row * 1024 + t * 4);
  u16x4 b4 = *(const u16x4*)(qpre1 + (size_t)row * 1024 + t * 4);
  float v[4];
  float s = 0.f, ss = 0.f;
#pragma unroll
  for (int j = 0; j < 4; ++j) {
    v[j] = b2f(a4[j]) + b2f(b4[j]) + ql_b[t * 4 + j];
    s += v[j]; ss += v[j] * v[j];
  }
#pragma unroll
  for (int off = 1; off < 64; off <<= 1) { s += __shfl_xor(s, off); ss += __shfl_xor(ss, off); }
  __shared__ float red[8];
  int wv = t >> 6, ln = t & 63;
  if (ln == 0) { red[wv] = s; red[4 + wv] = ss; }
  __syncthreads();
  s = red[0] + red[1] + red[2] + red[3];
  ss = red[4] + red[5] + red[6] + red[7];
  float mu = s * (1.f / 1024.f);
  float rstd = rsqrtf(ss * (1.f / 1024.f) - mu * mu + 1e-12f);
  int sidx = row >> 1, b = row & 1;
  int ch0 = t * 4;
  int hh = ch0 >> 6, hd0 = ch0 & 63;
  u16* dst = qatt + ((size_t)(b * 16 + hh) * 2048 + sidx) * 64 + hd0;
#pragma unroll
  for (int j = 0; j < 4; ++j) {
    int ch = ch0 + j;
    float gate = sigm(qs[ch]) * sigm(ks[ch]) * (LOG2E / 32.0f);
    float y = (v[j] - mu) * rstd * ln_g[ch] + ln_b[ch];
    dst[j] = f2b(y * gate);
  }
}

// ---- kernel 5: flash attention, swapped-QK in-register softmax, 128 keys per barrier.
// Two independent 64-key sub-chains per iteration: sub1's QK MFMAs overlap sub0's exp2/cvt_pk,
// barriers 32 -> 16, global prefetch distance doubled. setprio(1) around MFMA clusters (T5).
// K staged [key][ch] XOR-swizzled; V staged [ch][pi(key)] XOR-swizzled (both 0-conflict proven).
// grid 512: bh = bx & 31 (XCD L2 locality), qt = bx>>5.
__device__ __forceinline__ f32x4 mfma16(bf16x8 a, bf16x8 b, f32x4 c) {
  return __builtin_amdgcn_mfma_f32_16x16x32_bf16(a, b, c, 0, 0, 0);
}

__device__ __forceinline__ void qk64(const u16* kt0, const bf16x8 (&qf)[2][2],
                                     f32x4 (&sacc)[2][4], int l15, int colA, int colB) {
  __builtin_amdgcn_s_setprio(1);
#pragma unroll
  for (int nt = 0; nt < 4; ++nt) {
    const u16* krow = kt0 + (nt * 16 + l15) * 64;
    bf16x8 kA = *(const bf16x8*)(krow + colA);
    bf16x8 kB = *(const bf16x8*)(krow + colB);
    sacc[0][nt] = mfma16(kA, qf[0][0], sacc[0][nt]);
    sacc[0][nt] = mfma16(kB, qf[0][1], sacc[0][nt]);
    sacc[1][nt] = mfma16(kA, qf[1][0], sacc[1][nt]);
    sacc[1][nt] = mfma16(kB, qf[1][1], sacc[1][nt]);
  }
  __builtin_amdgcn_s_setprio(0);
}

__device__ __forceinline__ void softmax64(const f32x4 (&sacc)[2][4], float (&l_i)[2],
                                          bf16x8 (&pa)[2][2]) {
  union U8 { u32 w[4]; bf16x8 v; };
#pragma unroll
  for (int f = 0; f < 2; ++f) {
    float pe[4][4];
    float ls = 0.f;
#pragma unroll
    for (int nt = 0; nt < 4; ++nt) {
#pragma unroll
      for (int r = 0; r < 4; ++r) pe[nt][r] = __builtin_amdgcn_exp2f(sacc[f][nt][r]);
      ls += (pe[nt][0] + pe[nt][1]) + (pe[nt][2] + pe[nt][3]);
    }
    l_i[f] += ls;
    U8 t0, t1;
    t0.w[0] = cvtpk(pe[0][0], pe[0][1]); t0.w[1] = cvtpk(pe[0][2], pe[0][3]);
    t0.w[2] = cvtpk(pe[1][0], pe[1][1]); t0.w[3] = cvtpk(pe[1][2], pe[1][3]);
    t1.w[0] = cvtpk(pe[2][0], pe[2][1]); t1.w[1] = cvtpk(pe[2][2], pe[2][3]);
    t1.w[2] = cvtpk(pe[3][0], pe[3][1]); t1.w[3] = cvtpk(pe[3][2], pe[3][3]);
    pa[f][0] = t0.v; pa[f][1] = t1.v;
  }
}

__device__ __forceinline__ void pv64(const u16* vt0, const bf16x8 (&pa)[2][2],
                                     f32x4 (&oacc)[2][4], int l15, int colA, int colB) {
  __builtin_amdgcn_s_setprio(1);
#pragma unroll
  for (int nt = 0; nt < 4; ++nt) {
    const u16* vrow = vt0 + (nt * 16 + l15) * 64;
    bf16x8 vA = *(const bf16x8*)(vrow + colA);
    bf16x8 vB = *(const bf16x8*)(vrow + colB);
    oacc[0][nt] = mfma16(pa[0][0], vA, oacc[0][nt]);
    oacc[0][nt] = mfma16(pa[0][1], vB, oacc[0][nt]);
    oacc[1][nt] = mfma16(pa[1][0], vA, oacc[1][nt]);
    oacc[1][nt] = mfma16(pa[1][1], vB, oacc[1][nt]);
  }
  __builtin_amdgcn_s_setprio(0);
}

template <int CUR>
__device__ __forceinline__ void attn_iter2(bool pref,
                                           const bf16x8 (&qf)[2][2],
                                           const u16*& kp, const u16*& vp,
                                           u16 (&Ks)[2][2][64 * 64], u16 (&Vt)[2][2][64 * 64],
                                           f32x4 (&oacc)[2][4], float (&l_i)[2],
                                           int kdst, int chbase, int pcol,
                                           int l15, int colA, int colB) {
  // global prefetch of next 128-key tile first (longest load->use distance)
  u16x8 kr0, kr1, kr2, kr3, va0, vq0, va1, vq1;
  if (pref) {
    kp += 128 * 2048;
    kr0 = *(const u16x8*)kp;
    kr1 = *(const u16x8*)(kp + (size_t)32 * 2048);
    kr2 = *(const u16x8*)(kp + (size_t)64 * 2048);
    kr3 = *(const u16x8*)(kp + (size_t)96 * 2048);
    vp += 128 * 2048;
    va0 = *(const u16x8*)vp;
    vq0 = *(const u16x8*)(vp + 2048);
    va1 = *(const u16x8*)(vp + (size_t)64 * 2048);
    vq1 = *(const u16x8*)(vp + (size_t)64 * 2048 + 2048);
  }
  // sub 0: QK
  f32x4 s0[2][4] = {};
  qk64(Ks[CUR][0], qf, s0, l15, colA, colB);
  // sub 0 softmax (trans/VALU) || sub 1 QK (MFMA+LDS) - independent chains
  bf16x8 pa0[2][2];
  softmax64(s0, l_i, pa0);
  f32x4 s1[2][4] = {};
  qk64(Ks[CUR][1], qf, s1, l15, colA, colB);
  // sub 0 PV || sub 1 softmax
  pv64(Vt[CUR][0], pa0, oacc, l15, colA, colB);
  bf16x8 pa1[2][2];
  softmax64(s1, l_i, pa1);
  // sub 1 PV
  pv64(Vt[CUR][1], pa1, oacc, l15, colA, colB);
  // stage next tile into other buffer (readers finished at previous barrier)
  if (pref) {
    u16* kd0 = (u16*)Ks[CUR ^ 1][0];
    u16* kd1 = (u16*)Ks[CUR ^ 1][1];
    *(u16x8*)(kd0 + kdst) = kr0;
    *(u16x8*)(kd0 + kdst + 2048) = kr1;
    *(u16x8*)(kd1 + kdst) = kr2;
    *(u16x8*)(kd1 + kdst + 2048) = kr3;
    u16* vd0 = (u16*)Vt[CUR ^ 1][0];
    u16* vd1 = (u16*)Vt[CUR ^ 1][1];
#pragma unroll
    for (int c = 0; c < 8; ++c) {
      u32 p0 = (u32)va0[c] | ((u32)vq0[c] << 16);
      u32 p1 = (u32)va1[c] | ((u32)vq1[c] << 16);
      int ofs = (chbase + c) * 64 + (pcol ^ (c << 3));
      *(u32*)&vd0[ofs] = p0;
      *(u32*)&vd1[ofs] = p1;
    }
  }
  __syncthreads();
}

__global__ __launch_bounds__(256, 2) void k_attn(const u16* __restrict__ qatt,
                                                 const u16* __restrict__ key,
                                                 const u16* __restrict__ value,
                                                 const float* __restrict__ hbuf,
                                                 float* __restrict__ out) {
  int bh = blockIdx.x & 31;
  int qt = blockIdx.x >> 5;
  int b = bh >> 4, h = bh & 15;
  int tid = threadIdx.x, wave = tid >> 6, lane = tid & 63;
  int l15 = lane & 15, quad = lane >> 4;
  int q0 = qt * 128;

  __shared__ __align__(16) u16 Ks[2][2][64 * 64];   // [buf][sub][key][ch], XOR-swizzled 128B rows
  __shared__ __align__(16) u16 Vt[2][2][64 * 64];   // [buf][sub][ch][pi(key)], XOR-swizzled

  // Q B-frags: frag f covers queries q0 + f*64 + wave*16 + [0,16); lane holds Q[qrow=l15][ch=quad*8..]
  bf16x8 qf[2][2];
#pragma unroll
  for (int f = 0; f < 2; ++f) {
    const u16* qrow = qatt + ((size_t)bh * 2048 + q0 + f * 64 + wave * 16 + l15) * 64 + quad * 8;
    qf[f][0] = *(const bf16x8*)qrow;
    qf[f][1] = *(const bf16x8*)(qrow + 32);
  }

  const u16* kb = key + (size_t)b * 1024 + (size_t)h * 64;
  const u16* vb = value + (size_t)b * 1024 + (size_t)h * 64;

  // K staging: thread t covers rows {r, r+32, r+64, r+96}, r = t>>3, ch chunk (t&7)*8
  int krow = tid >> 3;
  int kchk = (tid & 7) * 8;
  const u16* kp = kb + (size_t)krow * 2048 + kchk;
  int kdst = krow * 64 + (kchk ^ ((krow & 7) << 3));

  // V staging: lane covers keys 2p,2p+1 (p=lane&31) of each sub, 8 ch at chbase; col = pi(2p)
  int p = lane & 31;
  int chbase = wave * 16 + (lane >> 5) * 8;
  const u16* vp = vb + (size_t)2 * p * 2048 + chbase;
  int kk = 2 * p;
  int pcol = ((kk >> 5) & 1) * 32 + ((kk >> 2) & 3) * 8 + ((kk >> 4) & 1) * 4 + (kk & 3);
  int swr = (l15 & 7) << 3;            // read-side row swizzle (u16 units)
  int colA = (8 * quad) ^ swr;
  int colB = (32 + 8 * quad) ^ swr;

  // prologue: tile 0 (128 keys) into buf 0
  {
    u16x8 kr0 = *(const u16x8*)kp;
    u16x8 kr1 = *(const u16x8*)(kp + (size_t)32 * 2048);
    u16x8 kr2 = *(const u16x8*)(kp + (size_t)64 * 2048);
    u16x8 kr3 = *(const u16x8*)(kp + (size_t)96 * 2048);
    *(u16x8*)(&Ks[0][0][kdst]) = kr0;
    *(u16x8*)(&Ks[0][0][kdst + 2048]) = kr1;
    *(u16x8*)(&Ks[0][1][kdst]) = kr2;
    *(u16x8*)(&Ks[0][1][kdst + 2048]) = kr3;
    u16x8 va0 = *(const u16x8*)vp;
    u16x8 vq0 = *(const u16x8*)(vp + 2048);
    u16x8 va1 = *(const u16x8*)(vp + (size_t)64 * 2048);
    u16x8 vq1 = *(const u16x8*)(vp + (size_t)64 * 2048 + 2048);
#pragma unroll
    for (int c = 0; c < 8; ++c) {
      u32 p0 = (u32)va0[c] | ((u32)vq0[c] << 16);
      u32 p1 = (u32)va1[c] | ((u32)vq1[c] << 16);
      int ofs = (chbase + c) * 64 + (pcol ^ (c << 3));
      *(u32*)&Vt[0][0][ofs] = p0;
      *(u32*)&Vt[0][1][ofs] = p1;
    }
  }
  __syncthreads();

  f32x4 oacc[2][4] = {};
  float l_i[2] = {};

  for (int kt = 0; kt < 16; kt += 2) {
    attn_iter2<0>(true, qf, kp, vp, Ks, Vt, oacc, l_i, kdst, chbase, pcol, l15, colA, colB);
    attn_iter2<1>(kt < 14, qf, kp, vp, Ks, Vt, oacc, l_i, kdst, chbase, pcol, l15, colA, colB);
  }

  // l reduction: lane holds partial for qrow=l15; sum across quads
#pragma unroll
  for (int f = 0; f < 2; ++f) {
    float l = l_i[f];
    l += __shfl_xor(l, 16);
    l += __shfl_xor(l, 32);
    l_i[f] = l;
  }
  // vsig inline (h holds MLP pre-activations: c = h[ch], f = h[1024+ch])
  float vsg[4];
#pragma unroll
  for (int nt = 0; nt < 4; ++nt) {
    int ch = h * 64 + nt * 16 + l15;
    vsg[nt] = sigm(hbuf[1024 + ch]) * tanhf(hbuf[ch]);
  }
  // epilogue: oacc[f][nt][r] = O[qrow=quad*4+r (+f*16)][ch=nt*16+l15]; /l, *vsig, write (s,b,H) fp32
#pragma unroll
  for (int f = 0; f < 2; ++f)
#pragma unroll
    for (int r = 0; r < 4; ++r) {
      int sq = q0 + f * 64 + wave * 16 + quad * 4 + r;
      float inv = 1.0f / __shfl(l_i[f], quad * 4 + r);
      float* orow = out + ((size_t)sq * 2 + b) * 1024 + h * 64;
#pragma unroll
      for (int nt = 0; nt < 4; ++nt)
        orow[nt * 16 + l15] = oacc[f][nt][r] * inv * vsg[nt];
    }
}

extern "C" void kernel_launch(void* const* d_in, const int* in_sizes, int n_in,
                              void* d_out, int out_size, void* d_ws, size_t ws_size,
                              hipStream_t stream) {
  (void)in_sizes; (void)n_in; (void)out_size; (void)ws_size;
  const float* query = (const float*)d_in[0];
  const float* key   = (const float*)d_in[1];
  const float* value = (const float*)d_in[2];
  const float* qs    = (const float*)d_in[3];
  const float* ksp   = (const float*)d_in[4];
  const float* vs    = (const float*)d_in[5];
  const float* vq_w  = (const float*)d_in[6];
  const float* vq_b  = (const float*)d_in[7];
  const float* ql_w  = (const float*)d_in[8];
  const float* ql_b  = (const float*)d_in[9];
  const float* ln_g  = (const float*)d_in[10];
  const float* ln_b  = (const float*)d_in[11];
  float* out = (float*)d_out;

  float* ws = (float*)d_ws;
  float* h   = ws;                                  // 2048 f32
  u16* qpre  = (u16*)(ws + 4096);                   // 2 x 4096x1024 bf16 (16 MB)
  u16* qbf   = qpre + (size_t)2 * 4096 * 1024;      // query bf16 (16 MB); qatt aliases
  u16* qatt  = qbf;                                 // 32x2048x64 bf16 (ln writes after gemm reads)
  u16* wbf   = qbf + (size_t)4096 * 2048;           // ql_w bf16 (4 MB)
  u16* kbf   = wbf + (size_t)1024 * 2048;           // key bf16 (8 MB)
  u16* vbf   = kbf + (size_t)4096 * 1024;           // value bf16 (8 MB)

  hipLaunchKernelGGL(k_cvt_h, dim3(18944), dim3(256), 0, stream,
                     (const float4*)query, (u16x4*)qbf,
                     (const float4*)ql_w,  (u16x4*)wbf,
                     (const float4*)key,   (u16x4*)kbf,
                     (const float4*)value, (u16x4*)vbf,
                     vs, vq_w, vq_b, h);
  hipLaunchKernelGGL(k_gemm, dim3(512),  dim3(256), 0, stream, qbf, wbf, qpre);
  hipLaunchKernelGGL(k_ln,   dim3(4096), dim3(256), 0, stream, qpre, qpre + (size_t)4096 * 1024,
                     ql_b, ln_g, ln_b, qs, ksp, qatt);
  hipLaunchKernelGGL(k_attn, dim3(512),  dim3(256), 0, stream, qatt, kbf, vbf, h, out);
}

// Round 4
// 215.313 us; speedup vs baseline: 1.2000x; 1.0222x over previous
//
#include <hip/hip_runtime.h>

typedef __bf16 bf16x8 __attribute__((ext_vector_type(8)));
typedef float f32x4 __attribute__((ext_vector_type(4)));
typedef unsigned short u16x8 __attribute__((ext_vector_type(8)));
typedef unsigned short u16x4 __attribute__((ext_vector_type(4)));
typedef unsigned short u16;
typedef unsigned int u32;

// S=2048, B=2, H=1024, NH=16, HD=64, SCALE=32 (exact)
// Inputs fp32, output fp32. Internal: bf16 MFMA, fp32 accum.
// Softmax is max-free (scores tightly bounded); log2(e) folded into q gate -> exp2 direct.

#define LOG2E 1.4426950408889634f

__device__ __forceinline__ float b2f(u16 u) {
  union { unsigned int i; float f; } x; x.i = ((unsigned int)u) << 16; return x.f;
}
__device__ __forceinline__ u16 f2b(float f) {
  union { float f; unsigned int i; } x; x.f = f;
  unsigned int r = (x.i + 0x7fffu + ((x.i >> 16) & 1u)) >> 16;
  return (u16)r;
}
__device__ __forceinline__ float sigm(float x) { return 1.0f / (1.0f + __expf(-x)); }
__device__ __forceinline__ u32 cvtpk(float lo, float hi) {
  u32 r; asm("v_cvt_pk_bf16_f32 %0, %1, %2" : "=v"(r) : "v"(lo), "v"(hi)); return r;
}

__device__ __forceinline__ void async16(u16* lds, const u16* g) {
  __builtin_amdgcn_global_load_lds((const __attribute__((address_space(1))) void*)g,
                                   (__attribute__((address_space(3))) void*)lds, 16, 0, 0);
}

// ---- kernel 0: fp32->bf16 conversions (grid-stride) + h MLP + gate precompute
// grid 2564: [0,2048) cvt over 18432 virtual tiles; [2048,2560) h rows; [2560,2564) gate.
__global__ __launch_bounds__(256) void k_cvt_h(const float4* __restrict__ q, u16x4* __restrict__ qd,
                                               const float4* __restrict__ w, u16x4* __restrict__ wd,
                                               const float4* __restrict__ k, u16x4* __restrict__ kd,
                                               const float4* __restrict__ v, u16x4* __restrict__ vd,
                                               const float* __restrict__ vs,
                                               const float* __restrict__ vq_w,
                                               const float* __restrict__ vq_b,
                                               float* __restrict__ h,
                                               const float* __restrict__ qs,
                                               const float* __restrict__ ks,
                                               float* __restrict__ gate) {
  __shared__ float svs[1024];
  int b = blockIdx.x;
  int t = threadIdx.x;
  if (b < 2048) {
#pragma unroll
    for (int vb = b; vb < 18432; vb += 2048) {
      const float4* s; u16x4* d; int i;
      if (vb < 8192)       { s = q; d = qd; i = vb * 256 + t; }
      else if (vb < 10240) { s = w; d = wd; i = (vb - 8192) * 256 + t; }
      else if (vb < 14336) { s = k; d = kd; i = (vb - 10240) * 256 + t; }
      else                 { s = v; d = vd; i = (vb - 14336) * 256 + t; }
      float4 x = s[i];
      u16x4 o; o[0] = f2b(x.x); o[1] = f2b(x.y); o[2] = f2b(x.z); o[3] = f2b(x.w);
      d[i] = o;
    }
    return;
  }
  if (b < 2560) {
    // h = sigmoid(vs) @ vq_w.T + vq_b  (wave per row)
    for (int i = t; i < 1024; i += 256) svs[i] = sigm(vs[i]);
    __syncthreads();
    int wave = t >> 6, lane = t & 63;
    int row = (b - 2048) * 4 + wave;
    const float4* w4 = (const float4*)(vq_w + (size_t)row * 1024);
    const float4* s4 = (const float4*)svs;
    float acc = 0.f;
#pragma unroll
    for (int kk = 0; kk < 4; ++kk) {
      float4 wv = w4[kk * 64 + lane];
      float4 sv = s4[kk * 64 + lane];
      acc += wv.x * sv.x + wv.y * sv.y + wv.z * sv.z + wv.w * sv.w;
    }
#pragma unroll
    for (int off = 1; off < 64; off <<= 1) acc += __shfl_xor(acc, off);
    if (lane == 0) h[row] = acc + vq_b[row];
    return;
  }
  // gate[ch] = sigm(qs)*sigm(ks)*log2e/32, computed ONCE (was per-row in k_ln)
  int ch = (b - 2560) * 256 + t;
  gate[ch] = sigm(qs[ch]) * sigm(ks[ch]) * (LOG2E / 32.0f);
}

// ---- kernel 3: qpre = query @ ql_w^T, split-K=2. 64x128 tiles, grid 1024 (4 blocks/CU).
__global__ __launch_bounds__(256) void k_gemm(const u16* __restrict__ A,    // 4096 x 2048 bf16
                                              const u16* __restrict__ Bt,   // 1024 x 2048 bf16
                                              u16* __restrict__ C) {        // 2 x (4096 x 1024)
  __shared__ __align__(16) u16 As[64 * 32];
  __shared__ __align__(16) u16 Bs[128 * 32];
  int tid = threadIdx.x;
  int wave = tid >> 6, lane = tid & 63;
  int l15 = lane & 15, quad = lane >> 4;
  int bx = blockIdx.x & 511;
  int kh = blockIdx.x >> 9;
  int kofs = kh << 10;
  int m0 = (bx >> 3) * 64;
  int n0 = (bx & 7) * 128;
  int wm = (wave >> 1) * 32, wn = (wave & 1) * 64;
  f32x4 acc[2][4] = {};
  int c1 = tid, c2 = tid + 256;
  const u16* gaA = A + (size_t)(m0 + (c1 >> 2)) * 2048 + kofs + (c1 & 3) * 8;
  const u16* gb1 = Bt + (size_t)(n0 + (c1 >> 2)) * 2048 + kofs + (c1 & 3) * 8;
  const u16* gb2 = Bt + (size_t)(n0 + (c2 >> 2)) * 2048 + kofs + (c2 & 3) * 8;
  u16* lA1 = As + wave * 512;
  u16* lB1 = Bs + wave * 512;
  u16* lB2 = Bs + 2048 + wave * 512;
  for (int kt = 0; kt < 32; ++kt) {
    async16(lA1, gaA);
    async16(lB1, gb1); async16(lB2, gb2);
    gaA += 32; gb1 += 32; gb2 += 32;
    __syncthreads();
    bf16x8 af[2], bfr[4];
#pragma unroll
    for (int mt = 0; mt < 2; ++mt)
      af[mt] = *(const bf16x8*)(As + (wm + mt * 16 + l15) * 32 + quad * 8);
#pragma unroll
    for (int nt = 0; nt < 4; ++nt)
      bfr[nt] = *(const bf16x8*)(Bs + (wn + nt * 16 + l15) * 32 + quad * 8);
#pragma unroll
    for (int mt = 0; mt < 2; ++mt)
#pragma unroll
      for (int nt = 0; nt < 4; ++nt)
        acc[mt][nt] = __builtin_amdgcn_mfma_f32_16x16x32_bf16(af[mt], bfr[nt], acc[mt][nt], 0, 0, 0);
    __syncthreads();
  }
  u16* Cp = C + (size_t)kh * 4096 * 1024;
#pragma unroll
  for (int mt = 0; mt < 2; ++mt) {
#pragma unroll
    for (int r = 0; r < 4; ++r) {
      int m = m0 + wm + mt * 16 + quad * 4 + r;
      u16* crow = Cp + (size_t)m * 1024 + n0 + wn + l15;
#pragma unroll
      for (int nt = 0; nt < 4; ++nt) crow[nt * 16] = f2b(acc[mt][nt][r]);
    }
  }
}

// ---- kernel 4: LN((qpre0+qpre1)+ql_b)*ln_g+ln_b, * gate -> qatt (b,h,s,hd)
// Wave-per-row: 16 ch/lane, shuffle-only reduction, zero barriers, gate precomputed. Grid 1024.
__global__ __launch_bounds__(256) void k_ln(const u16* __restrict__ qpre0,
                                            const u16* __restrict__ qpre1,
                                            const float* __restrict__ ql_b,
                                            const float* __restrict__ ln_g,
                                            const float* __restrict__ ln_b,
                                            const float* __restrict__ gate,
                                            u16* __restrict__ qatt) {
  int t = threadIdx.x;
  int wave = t >> 6, lane = t & 63;
  int row = blockIdx.x * 4 + wave;     // row = s*2 + b
  int ch0 = lane * 16;
  const u16* p0 = qpre0 + (size_t)row * 1024 + ch0;
  const u16* p1 = qpre1 + (size_t)row * 1024 + ch0;
  u16x8 a0 = *(const u16x8*)p0;
  u16x8 a1 = *(const u16x8*)(p0 + 8);
  u16x8 c0 = *(const u16x8*)p1;
  u16x8 c1 = *(const u16x8*)(p1 + 8);
  float qb[16];
#pragma unroll
  for (int i = 0; i < 4; ++i) *(float4*)&qb[i * 4] = *(const float4*)(ql_b + ch0 + i * 4);
  float v[16];
  float s = 0.f, ss = 0.f;
#pragma unroll
  for (int j = 0; j < 8; ++j) {
    v[j] = b2f(a0[j]) + b2f(c0[j]) + qb[j];
    v[8 + j] = b2f(a1[j]) + b2f(c1[j]) + qb[8 + j];
  }
#pragma unroll
  for (int j = 0; j < 16; ++j) { s += v[j]; ss += v[j] * v[j]; }
#pragma unroll
  for (int off = 1; off < 64; off <<= 1) { s += __shfl_xor(s, off); ss += __shfl_xor(ss, off); }
  float mu = s * (1.f / 1024.f);
  float rstd = rsqrtf(ss * (1.f / 1024.f) - mu * mu + 1e-12f);
  float g_[16], bb[16], gt[16];
#pragma unroll
  for (int i = 0; i < 4; ++i) {
    *(float4*)&g_[i * 4] = *(const float4*)(ln_g + ch0 + i * 4);
    *(float4*)&bb[i * 4] = *(const float4*)(ln_b + ch0 + i * 4);
    *(float4*)&gt[i * 4] = *(const float4*)(gate + ch0 + i * 4);
  }
  int sidx = row >> 1, b = row & 1;
  int hh = ch0 >> 6, hd0 = ch0 & 63;
  u16* dst = qatt + ((size_t)(b * 16 + hh) * 2048 + sidx) * 64 + hd0;
  u16x8 o0, o1;
#pragma unroll
  for (int j = 0; j < 8; ++j) {
    o0[j] = f2b(((v[j] - mu) * rstd * g_[j] + bb[j]) * gt[j]);
    o1[j] = f2b(((v[8 + j] - mu) * rstd * g_[8 + j] + bb[8 + j]) * gt[8 + j]);
  }
  *(u16x8*)dst = o0;
  *(u16x8*)(dst + 8) = o1;
}

// ---- kernel 5: flash attention, swapped-QK in-register softmax + LDS-staged K/V (round-2 best)
// + setprio(1) around MFMA clusters. grid 512: bh = bx & 31, qt = bx>>5.
__device__ __forceinline__ f32x4 mfma16(bf16x8 a, bf16x8 b, f32x4 c) {
  return __builtin_amdgcn_mfma_f32_16x16x32_bf16(a, b, c, 0, 0, 0);
}

template <int CUR>
__device__ __forceinline__ void attn_iter(bool pref,
                                          const bf16x8 (&qf)[2][2],
                                          const u16*& kp, const u16*& vp,
                                          u16 (&Ks)[2][64 * 64], u16 (&Vt)[2][64 * 64],
                                          f32x4 (&oacc)[2][4], float (&l_i)[2],
                                          int kdst, int chbase, int pcol,
                                          int l15, int colA, int colB) {
  // QK^T swapped: K A-frags from swizzled LDS. sacc[f][nt]: lane = S[key=quad*4+r+16nt][qrow=l15]
  f32x4 sacc[2][4] = {};
  const u16* kt0 = Ks[CUR];
  __builtin_amdgcn_s_setprio(1);
#pragma unroll
  for (int nt = 0; nt < 4; ++nt) {
    const u16* krow = kt0 + (nt * 16 + l15) * 64;
    bf16x8 kA = *(const bf16x8*)(krow + colA);
    bf16x8 kB = *(const bf16x8*)(krow + colB);
    sacc[0][nt] = mfma16(kA, qf[0][0], sacc[0][nt]);
    sacc[0][nt] = mfma16(kB, qf[0][1], sacc[0][nt]);
    sacc[1][nt] = mfma16(kA, qf[1][0], sacc[1][nt]);
    sacc[1][nt] = mfma16(kB, qf[1][1], sacc[1][nt]);
  }
  __builtin_amdgcn_s_setprio(0);
  // prefetch K(kt+1), V(kt+1) rows into registers (coalesced, 2+2 x 16B per thread)
  u16x8 kr0, kr1, va, vq;
  if (pref) {
    kp += 64 * 2048;
    kr0 = *(const u16x8*)kp;
    kr1 = *(const u16x8*)(kp + (size_t)32 * 2048);
    vp += 64 * 2048;
    va = *(const u16x8*)vp;
    vq = *(const u16x8*)(vp + 2048);
  }
  // softmax: p = 2^s (log2e folded into q gate); pack to bf16 in-register (zero cross-lane)
  u32 pw[2][8];
#pragma unroll
  for (int f = 0; f < 2; ++f) {
    float pe[4][4];
    float ls = 0.f;
#pragma unroll
    for (int nt = 0; nt < 4; ++nt) {
#pragma unroll
      for (int r = 0; r < 4; ++r) pe[nt][r] = __builtin_amdgcn_exp2f(sacc[f][nt][r]);
      ls += (pe[nt][0] + pe[nt][1]) + (pe[nt][2] + pe[nt][3]);
    }
    l_i[f] += ls;
    pw[f][0] = cvtpk(pe[0][0], pe[0][1]); pw[f][1] = cvtpk(pe[0][2], pe[0][3]);
    pw[f][2] = cvtpk(pe[1][0], pe[1][1]); pw[f][3] = cvtpk(pe[1][2], pe[1][3]);
    pw[f][4] = cvtpk(pe[2][0], pe[2][1]); pw[f][5] = cvtpk(pe[2][2], pe[2][3]);
    pw[f][6] = cvtpk(pe[3][0], pe[3][1]); pw[f][7] = cvtpk(pe[3][2], pe[3][3]);
  }
  union U8 { u32 w[4]; bf16x8 v; };
  bf16x8 pa[2][2];
#pragma unroll
  for (int f = 0; f < 2; ++f) {
    U8 t0; t0.w[0] = pw[f][0]; t0.w[1] = pw[f][1]; t0.w[2] = pw[f][2]; t0.w[3] = pw[f][3];
    U8 t1; t1.w[0] = pw[f][4]; t1.w[1] = pw[f][5]; t1.w[2] = pw[f][6]; t1.w[3] = pw[f][7];
    pa[f][0] = t0.v; pa[f][1] = t1.v;
  }
  // PV: V B-frags from swizzled, pi-permuted LDS
  const u16* vt0 = Vt[CUR];
  __builtin_amdgcn_s_setprio(1);
#pragma unroll
  for (int nt = 0; nt < 4; ++nt) {
    const u16* vrow = vt0 + (nt * 16 + l15) * 64;
    bf16x8 vA = *(const bf16x8*)(vrow + colA);
    bf16x8 vB = *(const bf16x8*)(vrow + colB);
    oacc[0][nt] = mfma16(pa[0][0], vA, oacc[0][nt]);
    oacc[0][nt] = mfma16(pa[0][1], vB, oacc[0][nt]);
    oacc[1][nt] = mfma16(pa[1][0], vA, oacc[1][nt]);
    oacc[1][nt] = mfma16(pa[1][1], vB, oacc[1][nt]);
  }
  __builtin_amdgcn_s_setprio(0);
  // stage K(kt+1), V(kt+1) into other buffer (readers finished at previous barrier)
  if (pref) {
    u16* kd = (u16*)Ks[CUR ^ 1];
    *(u16x8*)(kd + kdst) = kr0;
    *(u16x8*)(kd + kdst + 2048) = kr1;
    u16* vd = (u16*)Vt[CUR ^ 1];
#pragma unroll
    for (int c = 0; c < 8; ++c) {
      u32 pk2 = (u32)va[c] | ((u32)vq[c] << 16);
      *(u32*)&vd[(chbase + c) * 64 + (pcol ^ (c << 3))] = pk2;
    }
  }
  __syncthreads();
}

__global__ __launch_bounds__(256, 2) void k_attn(const u16* __restrict__ qatt,
                                                 const u16* __restrict__ key,
                                                 const u16* __restrict__ value,
                                                 const float* __restrict__ hbuf,
                                                 float* __restrict__ out) {
  int bh = blockIdx.x & 31;
  int qt = blockIdx.x >> 5;
  int b = bh >> 4, h = bh & 15;
  int tid = threadIdx.x, wave = tid >> 6, lane = tid & 63;
  int l15 = lane & 15, quad = lane >> 4;
  int q0 = qt * 128;

  __shared__ __align__(16) u16 Ks[2][64 * 64];   // [buf][key][ch], XOR-swizzled 128B rows
  __shared__ __align__(16) u16 Vt[2][64 * 64];   // [buf][ch][pi(key)], XOR-swizzled 128B rows

  // Q B-frags: frag f covers queries q0 + f*64 + wave*16 + [0,16); lane holds Q[qrow=l15][ch=quad*8..]
  bf16x8 qf[2][2];
#pragma unroll
  for (int f = 0; f < 2; ++f) {
    const u16* qrow = qatt + ((size_t)bh * 2048 + q0 + f * 64 + wave * 16 + l15) * 64 + quad * 8;
    qf[f][0] = *(const bf16x8*)qrow;
    qf[f][1] = *(const bf16x8*)(qrow + 32);
  }

  const u16* kb = key + (size_t)b * 1024 + (size_t)h * 64;
  const u16* vb = value + (size_t)b * 1024 + (size_t)h * 64;

  // K staging: thread t covers rows {t>>3, 32+(t>>3)}, ch chunk (t&7)*8 (128B row segments, coalesced)
  int krow = tid >> 3;
  int kchk = (tid & 7) * 8;
  const u16* kp = kb + (size_t)krow * 2048 + kchk;
  int kdst = krow * 64 + (kchk ^ ((krow & 7) << 3));   // +2048 for row+32 (same &7)

  // V staging: lane covers keys 2p,2p+1 (p=lane&31), 8 ch at chbase; scatter col = pi(2p)
  int p = lane & 31;
  int chbase = wave * 16 + (lane >> 5) * 8;
  const u16* vp = vb + (size_t)2 * p * 2048 + chbase;
  int kk = 2 * p;
  int pcol = ((kk >> 5) & 1) * 32 + ((kk >> 2) & 3) * 8 + ((kk >> 4) & 1) * 4 + (kk & 3);
  int swr = (l15 & 7) << 3;            // read-side row swizzle (u16 units)
  int colA = (8 * quad) ^ swr;
  int colB = (32 + 8 * quad) ^ swr;

  // prologue: K(0) into Ks[0], V(0) into Vt[0]
  {
    u16x8 kr0 = *(const u16x8*)kp;
    u16x8 kr1 = *(const u16x8*)(kp + (size_t)32 * 2048);
    *(u16x8*)(&Ks[0][kdst]) = kr0;
    *(u16x8*)(&Ks[0][kdst + 2048]) = kr1;
    u16x8 va = *(const u16x8*)vp;
    u16x8 vq = *(const u16x8*)(vp + 2048);
#pragma unroll
    for (int c = 0; c < 8; ++c) {
      u32 pk2 = (u32)va[c] | ((u32)vq[c] << 16);
      *(u32*)&Vt[0][(chbase + c) * 64 + (pcol ^ (c << 3))] = pk2;
    }
  }
  __syncthreads();

  f32x4 oacc[2][4] = {};
  float l_i[2] = {};

  for (int kt = 0; kt < 32; kt += 2) {
    attn_iter<0>(true, qf, kp, vp, Ks, Vt, oacc, l_i, kdst, chbase, pcol, l15, colA, colB);
    attn_iter<1>(kt < 30, qf, kp, vp, Ks, Vt, oacc, l_i, kdst, chbase, pcol, l15, colA, colB);
  }

  // l reduction: lane holds partial for qrow=l15; sum across quads
#pragma unroll
  for (int f = 0; f < 2; ++f) {
    float l = l_i[f];
    l += __shfl_xor(l, 16);
    l += __shfl_xor(l, 32);
    l_i[f] = l;
  }
  // vsig inline (h holds MLP pre-activations: c = h[ch], f = h[1024+ch])
  float vsg[4];
#pragma unroll
  for (int nt = 0; nt < 4; ++nt) {
    int ch = h * 64 + nt * 16 + l15;
    vsg[nt] = sigm(hbuf[1024 + ch]) * tanhf(hbuf[ch]);
  }
  // epilogue: oacc[f][nt][r] = O[qrow=quad*4+r (+f*16)][ch=nt*16+l15]; /l, *vsig, write (s,b,H) fp32
#pragma unroll
  for (int f = 0; f < 2; ++f)
#pragma unroll
    for (int r = 0; r < 4; ++r) {
      int sq = q0 + f * 64 + wave * 16 + quad * 4 + r;
      float inv = 1.0f / __shfl(l_i[f], quad * 4 + r);
      float* orow = out + ((size_t)sq * 2 + b) * 1024 + h * 64;
#pragma unroll
      for (int nt = 0; nt < 4; ++nt)
        orow[nt * 16 + l15] = oacc[f][nt][r] * inv * vsg[nt];
    }
}

extern "C" void kernel_launch(void* const* d_in, const int* in_sizes, int n_in,
                              void* d_out, int out_size, void* d_ws, size_t ws_size,
                              hipStream_t stream) {
  (void)in_sizes; (void)n_in; (void)out_size; (void)ws_size;
  const float* query = (const float*)d_in[0];
  const float* key   = (const float*)d_in[1];
  const float* value = (const float*)d_in[2];
  const float* qs    = (const float*)d_in[3];
  const float* ksp   = (const float*)d_in[4];
  const float* vs    = (const float*)d_in[5];
  const float* vq_w  = (const float*)d_in[6];
  const float* vq_b  = (const float*)d_in[7];
  const float* ql_w  = (const float*)d_in[8];
  const float* ql_b  = (const float*)d_in[9];
  const float* ln_g  = (const float*)d_in[10];
  const float* ln_b  = (const float*)d_in[11];
  float* out = (float*)d_out;

  float* ws = (float*)d_ws;
  float* h    = ws;                                 // 2048 f32
  float* gate = ws + 2048;                          // 1024 f32
  u16* qpre  = (u16*)(ws + 4096);                   // 2 x 4096x1024 bf16 (16 MB)
  u16* qbf   = qpre + (size_t)2 * 4096 * 1024;      // query bf16 (16 MB); qatt aliases
  u16* qatt  = qbf;                                 // 32x2048x64 bf16 (ln writes after gemm reads)
  u16* wbf   = qbf + (size_t)4096 * 2048;           // ql_w bf16 (4 MB)
  u16* kbf   = wbf + (size_t)1024 * 2048;           // key bf16 (8 MB)
  u16* vbf   = kbf + (size_t)4096 * 1024;           // value bf16 (8 MB)

  hipLaunchKernelGGL(k_cvt_h, dim3(2564), dim3(256), 0, stream,
                     (const float4*)query, (u16x4*)qbf,
                     (const float4*)ql_w,  (u16x4*)wbf,
                     (const float4*)key,   (u16x4*)kbf,
                     (const float4*)value, (u16x4*)vbf,
                     vs, vq_w, vq_b, h, qs, ksp, gate);
  hipLaunchKernelGGL(k_gemm, dim3(1024), dim3(256), 0, stream, qbf, wbf, qpre);
  hipLaunchKernelGGL(k_ln,   dim3(1024), dim3(256), 0, stream, qpre, qpre + (size_t)4096 * 1024,
                     ql_b, ln_g, ln_b, gate, qatt);
  hipLaunchKernelGGL(k_attn, dim3(512),  dim3(256), 0, stream, qatt, kbf, vbf, h, out);
}